// Round 1
// baseline (344.137 us; speedup 1.0000x reference)
//
#include <hip/hip_runtime.h>
#include <math.h>

// SelectiveSSMBlock: B=2, L=2048, D=1024, N=16, R=64, fp32.
// R8: mega-fusion — delta+scan1+scan2+scan3 in ONE resident-grid kernel with
//     two software grid barriers (512 blocks = 2/CU guaranteed). del array
//     eliminated; x/xz read once; dl/xd live in registers across all phases.

#define LOG2E 1.44269504088896340736f
typedef float v2f __attribute__((ext_vector_type(2)));

__device__ __forceinline__ float fexp2(float v){
#if defined(__has_builtin)
#if __has_builtin(__builtin_amdgcn_exp2f)
  return __builtin_amdgcn_exp2f(v);
#else
  return exp2f(v);
#endif
#else
  return exp2f(v);
#endif
}

__device__ __forceinline__ float fsoftplus(float v){
  return fmaxf(v, 0.f) + __logf(1.f + __expf(-fabsf(v)));
}

// Software grid barrier: all 512 blocks resident by construction
// (launch_bounds(256,2) -> VGPR<=256 -> 8 waves/CU, LDS 14KB -> 2 blocks/CU).
// Counter zeroed by k_prep each launch (stream-ordered; kernel-boundary flush
// makes the zero globally visible). Release on arrive + acquire on spin +
// per-thread fence after: cross-XCD L2 wb/inv per gfx950 memory model.
__device__ __forceinline__ void gridbar(unsigned* ctr, unsigned nb){
  __syncthreads();
  if (threadIdx.x == 0){
    __hip_atomic_fetch_add(ctr, 1u, __ATOMIC_ACQ_REL, __HIP_MEMORY_SCOPE_AGENT);
    while (__hip_atomic_load(ctr, __ATOMIC_ACQUIRE, __HIP_MEMORY_SCOPE_AGENT) < nb){
      __builtin_amdgcn_s_sleep(2);
    }
  }
  __syncthreads();
  __threadfence();
}

// ---------------- prep (adds barrier-counter zeroing)
__global__ __launch_bounds__(256) void k_prep(const float* __restrict__ xpw,
                                              const float* __restrict__ dtw,
                                              const float* __restrict__ alog,
                                              const float* __restrict__ te,
                                              float* __restrict__ w2T,
                                              float* __restrict__ dtwT,
                                              float* __restrict__ A2,
                                              float* __restrict__ sg,
                                              unsigned* __restrict__ bars){
  __shared__ float sm[32 * 33];
  const int bid = blockIdx.x, t = threadIdx.x;
  const int lane = t & 31, srow = t >> 5;
  if (bid < 96){
    const int kt = bid / 3, ct = bid - kt * 3;
#pragma unroll
    for (int r = 0; r < 4; r++){
      const int cr = srow * 4 + r;
      sm[cr * 33 + lane] = xpw[(size_t)(ct * 32 + cr) * 1024 + kt * 32 + lane];
    }
    __syncthreads();
#pragma unroll
    for (int r = 0; r < 4; r++){
      const int kr = srow * 4 + r;
      const int kg = kt * 32 + kr;
      const float s = 1.f / (1.f + __expf(-te[kg]));
      w2T[(size_t)kg * 96 + ct * 32 + lane] = sm[lane * 33 + kr] * s;
    }
  } else if (bid < 160){
    const int idx = bid - 96, dti = idx >> 1, kt2 = idx & 1;
#pragma unroll
    for (int r = 0; r < 4; r++){
      const int cr = srow * 4 + r;
      sm[cr * 33 + lane] = dtw[(size_t)(dti * 32 + cr) * 64 + kt2 * 32 + lane];
    }
    __syncthreads();
#pragma unroll
    for (int r = 0; r < 4; r++){
      const int kr = srow * 4 + r;
      dtwT[(size_t)(kt2 * 32 + kr) * 1024 + dti * 32 + lane] = sm[lane * 33 + kr];
    }
  } else if (bid < 176){
    const int j = (bid - 160) * 1024 + t;
#pragma unroll
    for (int i = 0; i < 4; i++)
      A2[j + i * 256] = -__expf(alog[j + i * 256]) * LOG2E;
  } else {
#pragma unroll
    for (int i = 0; i < 4; i++){
      const int m = i * 256 + t;
      sg[m] = 1.f / (1.f + __expf(-te[m]));
    }
    if (t < 2) bars[t] = 0u;
  }
}

// ---------------- xz partial GEMM, K-split 8 (KC=128). Grid (16,3,8)=384.
__global__ __launch_bounds__(256) void k_xz(const float* __restrict__ x,
                                            const float* __restrict__ w2T,
                                            float* __restrict__ xzp){
  __shared__ float xT[32 * 257];
  const int t = threadIdx.x;
  const int row0 = blockIdx.x * 256;
  const int c0 = blockIdx.y * 32;
  const int kbase = blockIdx.z * 128;
  v2f acc[16];
#pragma unroll
  for (int c = 0; c < 16; c++) acc[c] = (v2f){0.f, 0.f};
  const int kq = t & 7, rsub = t >> 3;
  for (int kt = 0; kt < 4; ++kt){
    const int k0 = kbase + kt * 32;
    __syncthreads();
#pragma unroll
    for (int p = 0; p < 8; p++){
      const int r = p * 32 + rsub;
      const float4 v = *reinterpret_cast<const float4*>(&x[(size_t)(row0 + r) * 1024 + k0 + kq * 4]);
      xT[(kq * 4 + 0) * 257 + r] = v.x;
      xT[(kq * 4 + 1) * 257 + r] = v.y;
      xT[(kq * 4 + 2) * 257 + r] = v.z;
      xT[(kq * 4 + 3) * 257 + r] = v.w;
    }
    __syncthreads();
#pragma unroll 4
    for (int kk = 0; kk < 32; ++kk){
      const float xv = xT[kk * 257 + t];
      const v2f xv2 = {xv, xv};
      const v2f* wr = reinterpret_cast<const v2f*>(&w2T[(size_t)(k0 + kk) * 96 + c0]);
#pragma unroll
      for (int c = 0; c < 16; c++) acc[c] = acc[c] + xv2 * wr[c];
    }
  }
  float4* o = reinterpret_cast<float4*>(xzp + ((size_t)blockIdx.z * 4096 + row0 + t) * 96 + c0);
  const float4* av = reinterpret_cast<const float4*>(acc);
#pragma unroll
  for (int q = 0; q < 8; q++) o[q] = av[q];
}

// ---------------- reduce 8 partials -> xz
__global__ __launch_bounds__(256) void k_reduce(const float4* __restrict__ p,
                                                float4* __restrict__ xz){
  const int i = blockIdx.x * 256 + threadIdx.x;
  float4 r = p[i];
#pragma unroll
  for (int s = 1; s < 8; s++){
    const float4 a = p[(size_t)s * 98304 + i];
    r.x += a.x; r.y += a.y; r.z += a.z; r.w += a.w;
  }
  xz[i] = r;
}

// ---------------- fused delta + scan1 + scan2 + scan3.
// Grid (64,4,2) = 512 blocks x 256 threads = exactly 2 blocks/CU resident.
__global__ __launch_bounds__(256, 2) void k_fused(const float* __restrict__ x,
                                                  const float* __restrict__ xz,
                                                  const float* __restrict__ dtwT,
                                                  const float* __restrict__ dtb,
                                                  const float* __restrict__ A2,
                                                  const float* __restrict__ sg,
                                                  const float* __restrict__ Dpar,
                                                  float* __restrict__ S,
                                                  float* __restrict__ P,
                                                  float* __restrict__ H,
                                                  float* __restrict__ out,
                                                  unsigned* __restrict__ bars){
  __shared__ float xzd[32 * 64];   // delta-part rows [l][k]   8 KB
  __shared__ float bc[32 * 32];    // B,C rows [l][c] (B:0-15, C:16-31) 4 KB
  __shared__ float ls[256], lp[256];

  const int t = threadIdx.x;
  const int chunk = blockIdx.x, dgrp = blockIdx.y, b = blockIdx.z;
  const int d = dgrp * 256 + t;
  const int l0 = chunk * 32;
  const float* xzb = xz + (size_t)(b * 2048 + l0) * 96;
  const size_t xidx0 = (size_t)(b * 2048 + l0) * 1024 + d;

  // stage xz rows into LDS: 32 rows x 24 float4 = 768 float4, 3 per thread
  for (int i = t; i < 768; i += 256){
    const int r = i / 24;
    const int c4 = i - r * 24;
    const float4 v = *reinterpret_cast<const float4*>(xzb + r * 96 + c4 * 4);
    if (c4 < 16) *reinterpret_cast<float4*>(&xzd[r * 64 + c4 * 4]) = v;
    else         *reinterpret_cast<float4*>(&bc[r * 32 + (c4 - 16) * 4]) = v;
  }

  // per-thread params + x loads (issued before the LDS barrier)
  v2f wv[32];
#pragma unroll
  for (int k2 = 0; k2 < 32; k2++){
    wv[k2].x = dtwT[(size_t)(2 * k2) * 1024 + d];
    wv[k2].y = dtwT[(size_t)(2 * k2 + 1) * 1024 + d];
  }
  const float dtbv = dtb[d];
  const float sgv = sg[d];
  float xd[32];
#pragma unroll
  for (int li = 0; li < 32; ++li)
    xd[li] = x[xidx0 + (size_t)li * 1024] * sgv;

  float a2[16];
  {
    const float4* ap = reinterpret_cast<const float4*>(A2 + (size_t)d * 16);
#pragma unroll
    for (int q = 0; q < 4; q++){
      const float4 v = ap[q];
      a2[q*4] = v.x; a2[q*4+1] = v.y; a2[q*4+2] = v.z; a2[q*4+3] = v.w;
    }
  }
  bool uni = true;
#pragma unroll
  for (int n = 1; n < 16; n++) uni = uni && (a2[n] == a2[0]);

  __syncthreads();

  // ---- P0: delta GEMM from LDS rows (identical summation order to k_delta)
  float dl[32];
#pragma unroll
  for (int li = 0; li < 32; ++li){
    const float4* dp4 = reinterpret_cast<const float4*>(&xzd[li * 64]);
    v2f acc = {dtbv, 0.f};
#pragma unroll
    for (int k4 = 0; k4 < 16; k4++){
      const float4 xv = dp4[k4];
      acc = acc + (v2f){xv.x, xv.y} * wv[2 * k4];
      acc = acc + (v2f){xv.z, xv.w} * wv[2 * k4 + 1];
    }
    dl[li] = fsoftplus(acc.x + acc.y);
  }

  const size_t sbase = ((size_t)((b * 64 + chunk) * 1024 + d)) * 16;

  // ---- P1: local chunk scan -> S, P
  if (uni){
    const float a2u = a2[0];
    v2f h2[8];
#pragma unroll
    for (int q = 0; q < 8; q++) h2[q] = (v2f){0.f, 0.f};
    float sumd = 0.f;
#pragma unroll
    for (int li = 0; li < 32; ++li){
      sumd += dl[li];
      const float tt = fexp2(dl[li] * a2u);
      const float duv = dl[li] * xd[li];
      const v2f tt2 = {tt, tt}, du2 = {duv, duv};
      const float4* bq = reinterpret_cast<const float4*>(&bc[li * 32]);
#pragma unroll
      for (int q4 = 0; q4 < 4; q4++){
        const float4 bv = bq[q4];
        h2[2*q4]   = h2[2*q4]   * tt2 + (v2f){bv.x, bv.y} * du2;
        h2[2*q4+1] = h2[2*q4+1] * tt2 + (v2f){bv.z, bv.w} * du2;
      }
    }
    const float4* hv = reinterpret_cast<const float4*>(h2);
#pragma unroll
    for (int q = 0; q < 4; q++)
      *reinterpret_cast<float4*>(&S[sbase + q * 4]) = hv[q];
    const float Ppu = fexp2(a2u * sumd);
    const float4 pv = {Ppu, Ppu, Ppu, Ppu};
#pragma unroll
    for (int q = 0; q < 4; q++)
      *reinterpret_cast<float4*>(&P[sbase + q * 4]) = pv;
  } else {
    float h[16], Pp[16];
#pragma unroll
    for (int n = 0; n < 16; n++){ h[n] = 0.f; Pp[n] = 1.f; }
#pragma unroll
    for (int li = 0; li < 32; ++li){
      const float duv = dl[li] * xd[li];
#pragma unroll
      for (int n = 0; n < 16; n++){
        const float tt = fexp2(dl[li] * a2[n]);
        h[n] = fmaf(tt, h[n], duv * bc[li * 32 + n]);
        Pp[n] *= tt;
      }
    }
#pragma unroll
    for (int q = 0; q < 4; q++){
      float4 v; v.x = h[q*4]; v.y = h[q*4+1]; v.z = h[q*4+2]; v.w = h[q*4+3];
      *reinterpret_cast<float4*>(&S[sbase + q * 4]) = v;
      float4 u; u.x = Pp[q*4]; u.y = Pp[q*4+1]; u.z = Pp[q*4+2]; u.w = Pp[q*4+3];
      *reinterpret_cast<float4*>(&P[sbase + q * 4]) = u;
    }
  }

  gridbar(bars + 0, 512u);

  // ---- P2: cross-chunk combine (scan2 remapped onto this grid) -> H
  {
    const int bid = (blockIdx.z * 4 + blockIdx.y) * 64 + blockIdx.x; // 0..511
    const int b2 = bid >> 8, dq = bid & 255;
    const int seg = t >> 6, s = t & 63;         // 4 segs x 16 chunks
    const int d2 = dq * 4 + (s >> 4), n2 = s & 15;
    const size_t sb2 = ((size_t)(b2 * 64) * 1024 + d2) * 16 + n2;
    float Sv[16], Pv[16];
    float sa = 0.f, pa = 1.f;
#pragma unroll
    for (int i = 0; i < 16; i++){
      const size_t idx = sb2 + (size_t)(seg * 16 + i) * 16384;
      Sv[i] = S[idx]; Pv[i] = P[idx];
      sa = fmaf(Pv[i], sa, Sv[i]);
      pa *= Pv[i];
    }
    ls[t] = sa; lp[t] = pa;
    __syncthreads();
    float h = 0.f;
    for (int j = 0; j < seg; j++)
      h = fmaf(lp[j * 64 + s], h, ls[j * 64 + s]);
#pragma unroll
    for (int i = 0; i < 16; i++){
      const size_t idx = sb2 + (size_t)(seg * 16 + i) * 16384;
      H[idx] = h;
      h = fmaf(Pv[i], h, Sv[i]);
    }
  }

  gridbar(bars + 1, 512u);

  // ---- P3: replay with true init + y, from registers/LDS (no global re-read)
  const float Dv = Dpar[d];
  if (uni){
    const float a2u = a2[0];
    v2f h2[8];
    {
      const float4* hp = reinterpret_cast<const float4*>(H + sbase);
      float4* hd = reinterpret_cast<float4*>(h2);
#pragma unroll
      for (int q = 0; q < 4; q++) hd[q] = hp[q];
    }
#pragma unroll
    for (int li = 0; li < 32; ++li){
      const float tt = fexp2(dl[li] * a2u);
      const float duv = dl[li] * xd[li];
      const v2f tt2 = {tt, tt}, du2 = {duv, duv};
      const float4* bq = reinterpret_cast<const float4*>(&bc[li * 32]);
      const float4* cq = reinterpret_cast<const float4*>(&bc[li * 32 + 16]);
      v2f yv = {0.f, 0.f};
#pragma unroll
      for (int q4 = 0; q4 < 4; q4++){
        const float4 bv = bq[q4], cv = cq[q4];
        h2[2*q4]   = h2[2*q4]   * tt2 + (v2f){bv.x, bv.y} * du2;
        h2[2*q4+1] = h2[2*q4+1] * tt2 + (v2f){bv.z, bv.w} * du2;
        yv = yv + h2[2*q4] * (v2f){cv.x, cv.y} + h2[2*q4+1] * (v2f){cv.z, cv.w};
      }
      out[xidx0 + (size_t)li * 1024] = fmaf(xd[li], Dv, yv.x + yv.y);
    }
  } else {
    float h[16];
    {
      const float4* hp = reinterpret_cast<const float4*>(H + sbase);
#pragma unroll
      for (int q = 0; q < 4; q++){
        const float4 v = hp[q];
        h[q*4] = v.x; h[q*4+1] = v.y; h[q*4+2] = v.z; h[q*4+3] = v.w;
      }
    }
#pragma unroll
    for (int li = 0; li < 32; ++li){
      const float duv = dl[li] * xd[li];
      float y = 0.f;
#pragma unroll
      for (int n = 0; n < 16; n++){
        const float tt = fexp2(dl[li] * a2[n]);
        h[n] = fmaf(tt, h[n], duv * bc[li * 32 + n]);
        y = fmaf(h[n], bc[li * 32 + 16 + n], y);
      }
      out[xidx0 + (size_t)li * 1024] = fmaf(xd[li], Dv, y);
    }
  }
}

extern "C" void kernel_launch(void* const* d_in, const int* in_sizes, int n_in,
                              void* d_out, int out_size, void* d_ws, size_t ws_size,
                              hipStream_t stream){
  const float* x    = (const float*)d_in[0];
  const float* Alog = (const float*)d_in[1];
  const float* xpw  = (const float*)d_in[2];
  const float* dtw  = (const float*)d_in[3];
  const float* dtb  = (const float*)d_in[4];
  const float* Dpar = (const float*)d_in[5];
  const float* te   = (const float*)d_in[6];
  float* out = (float*)d_out;
  char* ws = (char*)d_ws;

  float* w2T  = (float*)(ws);             // 393216
  float* A2   = (float*)(ws + 393216);    // 65536
  float* sg   = (float*)(ws + 458752);    // 4096
  float* dtwT = (float*)(ws + 462848);    // 262144
  float* xz   = (float*)(ws + 724992);    // 1572864
  // (hole: former del region, unused)
  float* xzp  = (float*)(ws + 19075072);  // 12582912 (8 partials)
  float* S    = (float*)(ws + 31657984);  // 8388608 (B*64*D*N*4)
  float* P    = (float*)(ws + 40046592);  // 8388608
  float* Hst  = (float*)(ws + 48435200);  // 8388608
  unsigned* bars = (unsigned*)(ws + 56823808); // 8 bytes

  hipLaunchKernelGGL(k_prep,   dim3(177),      dim3(256), 0, stream, xpw, dtw, Alog, te, w2T, dtwT, A2, sg, bars);
  hipLaunchKernelGGL(k_xz,     dim3(16, 3, 8), dim3(256), 0, stream, x, w2T, xzp);
  hipLaunchKernelGGL(k_reduce, dim3(384),      dim3(256), 0, stream, (const float4*)xzp, (float4*)xz);
  hipLaunchKernelGGL(k_fused,  dim3(64, 4, 2), dim3(256), 0, stream, x, xz, dtwT, dtb, A2, sg, Dpar, S, P, Hst, out, bars);
}

// Round 3
// 264.186 us; speedup vs baseline: 1.3026x; 1.3026x over previous
//
#include <hip/hip_runtime.h>
#include <math.h>

// SelectiveSSMBlock: B=2, L=2048, D=1024, N=16, R=64, fp32.
// R10: R9 with the fence spelled as __builtin_amdgcn_fence (compile fix).
//     Barrier: release on arrive, RELAXED polls, single acquire fence by
//     thread0. Everything else byte-identical to R8/R9 for a clean A/B.

#define LOG2E 1.44269504088896340736f
typedef float v2f __attribute__((ext_vector_type(2)));

__device__ __forceinline__ float fexp2(float v){
#if defined(__has_builtin)
#if __has_builtin(__builtin_amdgcn_exp2f)
  return __builtin_amdgcn_exp2f(v);
#else
  return exp2f(v);
#endif
#else
  return exp2f(v);
#endif
}

__device__ __forceinline__ float fsoftplus(float v){
  return fmaxf(v, 0.f) + __logf(1.f + __expf(-fabsf(v)));
}

// Software grid barrier, all 512 blocks resident by construction.
// - __syncthreads drains each wave's vmem (compiler emits waitcnt before
//   s_barrier) -> block's writes are in L2 (L1 is write-through).
// - thread0: RELEASE fetch_add at agent scope = one L2 writeback + signal.
// - spin on RELAXED agent loads: reaches coherence point, NO per-poll inv.
// - one ACQUIRE fence (builtin, "agent") by thread0 after exit: single
//   cache-wide buffer_inv covering the whole block's subsequent reads.
__device__ __forceinline__ void gridbar(unsigned* ctr, unsigned nb){
  __syncthreads();
  if (threadIdx.x == 0){
    __hip_atomic_fetch_add(ctr, 1u, __ATOMIC_RELEASE, __HIP_MEMORY_SCOPE_AGENT);
    while (__hip_atomic_load(ctr, __ATOMIC_RELAXED, __HIP_MEMORY_SCOPE_AGENT) < nb){
      __builtin_amdgcn_s_sleep(8);
    }
    __builtin_amdgcn_fence(__ATOMIC_ACQUIRE, "agent");
  }
  __syncthreads();
}

// ---------------- prep (zeroes barrier counters each launch)
__global__ __launch_bounds__(256) void k_prep(const float* __restrict__ xpw,
                                              const float* __restrict__ dtw,
                                              const float* __restrict__ alog,
                                              const float* __restrict__ te,
                                              float* __restrict__ w2T,
                                              float* __restrict__ dtwT,
                                              float* __restrict__ A2,
                                              float* __restrict__ sg,
                                              unsigned* __restrict__ bars){
  __shared__ float sm[32 * 33];
  const int bid = blockIdx.x, t = threadIdx.x;
  const int lane = t & 31, srow = t >> 5;
  if (bid < 96){
    const int kt = bid / 3, ct = bid - kt * 3;
#pragma unroll
    for (int r = 0; r < 4; r++){
      const int cr = srow * 4 + r;
      sm[cr * 33 + lane] = xpw[(size_t)(ct * 32 + cr) * 1024 + kt * 32 + lane];
    }
    __syncthreads();
#pragma unroll
    for (int r = 0; r < 4; r++){
      const int kr = srow * 4 + r;
      const int kg = kt * 32 + kr;
      const float s = 1.f / (1.f + __expf(-te[kg]));
      w2T[(size_t)kg * 96 + ct * 32 + lane] = sm[lane * 33 + kr] * s;
    }
  } else if (bid < 160){
    const int idx = bid - 96, dti = idx >> 1, kt2 = idx & 1;
#pragma unroll
    for (int r = 0; r < 4; r++){
      const int cr = srow * 4 + r;
      sm[cr * 33 + lane] = dtw[(size_t)(dti * 32 + cr) * 64 + kt2 * 32 + lane];
    }
    __syncthreads();
#pragma unroll
    for (int r = 0; r < 4; r++){
      const int kr = srow * 4 + r;
      dtwT[(size_t)(kt2 * 32 + kr) * 1024 + dti * 32 + lane] = sm[lane * 33 + kr];
    }
  } else if (bid < 176){
    const int j = (bid - 160) * 1024 + t;
#pragma unroll
    for (int i = 0; i < 4; i++)
      A2[j + i * 256] = -__expf(alog[j + i * 256]) * LOG2E;
  } else {
#pragma unroll
    for (int i = 0; i < 4; i++){
      const int m = i * 256 + t;
      sg[m] = 1.f / (1.f + __expf(-te[m]));
    }
    if (t < 2) bars[t] = 0u;
  }
}

// ---------------- xz partial GEMM, K-split 8 (KC=128). Grid (16,3,8)=384.
__global__ __launch_bounds__(256) void k_xz(const float* __restrict__ x,
                                            const float* __restrict__ w2T,
                                            float* __restrict__ xzp){
  __shared__ float xT[32 * 257];
  const int t = threadIdx.x;
  const int row0 = blockIdx.x * 256;
  const int c0 = blockIdx.y * 32;
  const int kbase = blockIdx.z * 128;
  v2f acc[16];
#pragma unroll
  for (int c = 0; c < 16; c++) acc[c] = (v2f){0.f, 0.f};
  const int kq = t & 7, rsub = t >> 3;
  for (int kt = 0; kt < 4; ++kt){
    const int k0 = kbase + kt * 32;
    __syncthreads();
#pragma unroll
    for (int p = 0; p < 8; p++){
      const int r = p * 32 + rsub;
      const float4 v = *reinterpret_cast<const float4*>(&x[(size_t)(row0 + r) * 1024 + k0 + kq * 4]);
      xT[(kq * 4 + 0) * 257 + r] = v.x;
      xT[(kq * 4 + 1) * 257 + r] = v.y;
      xT[(kq * 4 + 2) * 257 + r] = v.z;
      xT[(kq * 4 + 3) * 257 + r] = v.w;
    }
    __syncthreads();
#pragma unroll 4
    for (int kk = 0; kk < 32; ++kk){
      const float xv = xT[kk * 257 + t];
      const v2f xv2 = {xv, xv};
      const v2f* wr = reinterpret_cast<const v2f*>(&w2T[(size_t)(k0 + kk) * 96 + c0]);
#pragma unroll
      for (int c = 0; c < 16; c++) acc[c] = acc[c] + xv2 * wr[c];
    }
  }
  float4* o = reinterpret_cast<float4*>(xzp + ((size_t)blockIdx.z * 4096 + row0 + t) * 96 + c0);
  const float4* av = reinterpret_cast<const float4*>(acc);
#pragma unroll
  for (int q = 0; q < 8; q++) o[q] = av[q];
}

// ---------------- reduce 8 partials -> xz
__global__ __launch_bounds__(256) void k_reduce(const float4* __restrict__ p,
                                                float4* __restrict__ xz){
  const int i = blockIdx.x * 256 + threadIdx.x;
  float4 r = p[i];
#pragma unroll
  for (int s = 1; s < 8; s++){
    const float4 a = p[(size_t)s * 98304 + i];
    r.x += a.x; r.y += a.y; r.z += a.z; r.w += a.w;
  }
  xz[i] = r;
}

// ---------------- fused delta + scan1 + scan2 + scan3.
// Grid (64,4,2) = 512 blocks x 256 threads = exactly 2 blocks/CU resident.
__global__ __launch_bounds__(256, 2) void k_fused(const float* __restrict__ x,
                                                  const float* __restrict__ xz,
                                                  const float* __restrict__ dtwT,
                                                  const float* __restrict__ dtb,
                                                  const float* __restrict__ A2,
                                                  const float* __restrict__ sg,
                                                  const float* __restrict__ Dpar,
                                                  float* __restrict__ S,
                                                  float* __restrict__ P,
                                                  float* __restrict__ H,
                                                  float* __restrict__ out,
                                                  unsigned* __restrict__ bars){
  __shared__ float xzd[32 * 64];   // delta-part rows [l][k]   8 KB
  __shared__ float bc[32 * 32];    // B,C rows [l][c] (B:0-15, C:16-31) 4 KB
  __shared__ float ls[256], lp[256];

  const int t = threadIdx.x;
  const int chunk = blockIdx.x, dgrp = blockIdx.y, b = blockIdx.z;
  const int d = dgrp * 256 + t;
  const int l0 = chunk * 32;
  const float* xzb = xz + (size_t)(b * 2048 + l0) * 96;
  const size_t xidx0 = (size_t)(b * 2048 + l0) * 1024 + d;

  // stage xz rows into LDS: 32 rows x 24 float4 = 768 float4, 3 per thread
  for (int i = t; i < 768; i += 256){
    const int r = i / 24;
    const int c4 = i - r * 24;
    const float4 v = *reinterpret_cast<const float4*>(xzb + r * 96 + c4 * 4);
    if (c4 < 16) *reinterpret_cast<float4*>(&xzd[r * 64 + c4 * 4]) = v;
    else         *reinterpret_cast<float4*>(&bc[r * 32 + (c4 - 16) * 4]) = v;
  }

  // per-thread params + x loads (issued before the LDS barrier)
  v2f wv[32];
#pragma unroll
  for (int k2 = 0; k2 < 32; k2++){
    wv[k2].x = dtwT[(size_t)(2 * k2) * 1024 + d];
    wv[k2].y = dtwT[(size_t)(2 * k2 + 1) * 1024 + d];
  }
  const float dtbv = dtb[d];
  const float sgv = sg[d];
  float xd[32];
#pragma unroll
  for (int li = 0; li < 32; ++li)
    xd[li] = x[xidx0 + (size_t)li * 1024] * sgv;

  float a2[16];
  {
    const float4* ap = reinterpret_cast<const float4*>(A2 + (size_t)d * 16);
#pragma unroll
    for (int q = 0; q < 4; q++){
      const float4 v = ap[q];
      a2[q*4] = v.x; a2[q*4+1] = v.y; a2[q*4+2] = v.z; a2[q*4+3] = v.w;
    }
  }
  bool uni = true;
#pragma unroll
  for (int n = 1; n < 16; n++) uni = uni && (a2[n] == a2[0]);

  __syncthreads();

  // ---- P0: delta GEMM from LDS rows (identical summation order to k_delta)
  float dl[32];
#pragma unroll
  for (int li = 0; li < 32; ++li){
    const float4* dp4 = reinterpret_cast<const float4*>(&xzd[li * 64]);
    v2f acc = {dtbv, 0.f};
#pragma unroll
    for (int k4 = 0; k4 < 16; k4++){
      const float4 xv = dp4[k4];
      acc = acc + (v2f){xv.x, xv.y} * wv[2 * k4];
      acc = acc + (v2f){xv.z, xv.w} * wv[2 * k4 + 1];
    }
    dl[li] = fsoftplus(acc.x + acc.y);
  }

  const size_t sbase = ((size_t)((b * 64 + chunk) * 1024 + d)) * 16;

  // ---- P1: local chunk scan -> S, P
  if (uni){
    const float a2u = a2[0];
    v2f h2[8];
#pragma unroll
    for (int q = 0; q < 8; q++) h2[q] = (v2f){0.f, 0.f};
    float sumd = 0.f;
#pragma unroll
    for (int li = 0; li < 32; ++li){
      sumd += dl[li];
      const float tt = fexp2(dl[li] * a2u);
      const float duv = dl[li] * xd[li];
      const v2f tt2 = {tt, tt}, du2 = {duv, duv};
      const float4* bq = reinterpret_cast<const float4*>(&bc[li * 32]);
#pragma unroll
      for (int q4 = 0; q4 < 4; q4++){
        const float4 bv = bq[q4];
        h2[2*q4]   = h2[2*q4]   * tt2 + (v2f){bv.x, bv.y} * du2;
        h2[2*q4+1] = h2[2*q4+1] * tt2 + (v2f){bv.z, bv.w} * du2;
      }
    }
    const float4* hv = reinterpret_cast<const float4*>(h2);
#pragma unroll
    for (int q = 0; q < 4; q++)
      *reinterpret_cast<float4*>(&S[sbase + q * 4]) = hv[q];
    const float Ppu = fexp2(a2u * sumd);
    const float4 pv = {Ppu, Ppu, Ppu, Ppu};
#pragma unroll
    for (int q = 0; q < 4; q++)
      *reinterpret_cast<float4*>(&P[sbase + q * 4]) = pv;
  } else {
    float h[16], Pp[16];
#pragma unroll
    for (int n = 0; n < 16; n++){ h[n] = 0.f; Pp[n] = 1.f; }
#pragma unroll
    for (int li = 0; li < 32; ++li){
      const float duv = dl[li] * xd[li];
#pragma unroll
      for (int n = 0; n < 16; n++){
        const float tt = fexp2(dl[li] * a2[n]);
        h[n] = fmaf(tt, h[n], duv * bc[li * 32 + n]);
        Pp[n] *= tt;
      }
    }
#pragma unroll
    for (int q = 0; q < 4; q++){
      float4 v; v.x = h[q*4]; v.y = h[q*4+1]; v.z = h[q*4+2]; v.w = h[q*4+3];
      *reinterpret_cast<float4*>(&S[sbase + q * 4]) = v;
      float4 u; u.x = Pp[q*4]; u.y = Pp[q*4+1]; u.z = Pp[q*4+2]; u.w = Pp[q*4+3];
      *reinterpret_cast<float4*>(&P[sbase + q * 4]) = u;
    }
  }

  gridbar(bars + 0, 512u);

  // ---- P2: cross-chunk combine (scan2 remapped onto this grid) -> H
  {
    const int bid = (blockIdx.z * 4 + blockIdx.y) * 64 + blockIdx.x; // 0..511
    const int b2 = bid >> 8, dq = bid & 255;
    const int seg = t >> 6, s = t & 63;         // 4 segs x 16 chunks
    const int d2 = dq * 4 + (s >> 4), n2 = s & 15;
    const size_t sb2 = ((size_t)(b2 * 64) * 1024 + d2) * 16 + n2;
    float Sv[16], Pv[16];
    float sa = 0.f, pa = 1.f;
#pragma unroll
    for (int i = 0; i < 16; i++){
      const size_t idx = sb2 + (size_t)(seg * 16 + i) * 16384;
      Sv[i] = S[idx]; Pv[i] = P[idx];
      sa = fmaf(Pv[i], sa, Sv[i]);
      pa *= Pv[i];
    }
    ls[t] = sa; lp[t] = pa;
    __syncthreads();
    float h = 0.f;
    for (int j = 0; j < seg; j++)
      h = fmaf(lp[j * 64 + s], h, ls[j * 64 + s]);
#pragma unroll
    for (int i = 0; i < 16; i++){
      const size_t idx = sb2 + (size_t)(seg * 16 + i) * 16384;
      H[idx] = h;
      h = fmaf(Pv[i], h, Sv[i]);
    }
  }

  gridbar(bars + 1, 512u);

  // ---- P3: replay with true init + y, from registers/LDS (no global re-read)
  const float Dv = Dpar[d];
  if (uni){
    const float a2u = a2[0];
    v2f h2[8];
    {
      const float4* hp = reinterpret_cast<const float4*>(H + sbase);
      float4* hd = reinterpret_cast<float4*>(h2);
#pragma unroll
      for (int q = 0; q < 4; q++) hd[q] = hp[q];
    }
#pragma unroll
    for (int li = 0; li < 32; ++li){
      const float tt = fexp2(dl[li] * a2u);
      const float duv = dl[li] * xd[li];
      const v2f tt2 = {tt, tt}, du2 = {duv, duv};
      const float4* bq = reinterpret_cast<const float4*>(&bc[li * 32]);
      const float4* cq = reinterpret_cast<const float4*>(&bc[li * 32 + 16]);
      v2f yv = {0.f, 0.f};
#pragma unroll
      for (int q4 = 0; q4 < 4; q4++){
        const float4 bv = bq[q4], cv = cq[q4];
        h2[2*q4]   = h2[2*q4]   * tt2 + (v2f){bv.x, bv.y} * du2;
        h2[2*q4+1] = h2[2*q4+1] * tt2 + (v2f){bv.z, bv.w} * du2;
        yv = yv + h2[2*q4] * (v2f){cv.x, cv.y} + h2[2*q4+1] * (v2f){cv.z, cv.w};
      }
      out[xidx0 + (size_t)li * 1024] = fmaf(xd[li], Dv, yv.x + yv.y);
    }
  } else {
    float h[16];
    {
      const float4* hp = reinterpret_cast<const float4*>(H + sbase);
#pragma unroll
      for (int q = 0; q < 4; q++){
        const float4 v = hp[q];
        h[q*4] = v.x; h[q*4+1] = v.y; h[q*4+2] = v.z; h[q*4+3] = v.w;
      }
    }
#pragma unroll
    for (int li = 0; li < 32; ++li){
      const float duv = dl[li] * xd[li];
      float y = 0.f;
#pragma unroll
      for (int n = 0; n < 16; n++){
        const float tt = fexp2(dl[li] * a2[n]);
        h[n] = fmaf(tt, h[n], duv * bc[li * 32 + n]);
        y = fmaf(h[n], bc[li * 32 + 16 + n], y);
      }
      out[xidx0 + (size_t)li * 1024] = fmaf(xd[li], Dv, y);
    }
  }
}

extern "C" void kernel_launch(void* const* d_in, const int* in_sizes, int n_in,
                              void* d_out, int out_size, void* d_ws, size_t ws_size,
                              hipStream_t stream){
  const float* x    = (const float*)d_in[0];
  const float* Alog = (const float*)d_in[1];
  const float* xpw  = (const float*)d_in[2];
  const float* dtw  = (const float*)d_in[3];
  const float* dtb  = (const float*)d_in[4];
  const float* Dpar = (const float*)d_in[5];
  const float* te   = (const float*)d_in[6];
  float* out = (float*)d_out;
  char* ws = (char*)d_ws;

  float* w2T  = (float*)(ws);             // 393216
  float* A2   = (float*)(ws + 393216);    // 65536
  float* sg   = (float*)(ws + 458752);    // 4096
  float* dtwT = (float*)(ws + 462848);    // 262144
  float* xz   = (float*)(ws + 724992);    // 1572864
  // (hole: former del region, unused)
  float* xzp  = (float*)(ws + 19075072);  // 12582912 (8 partials)
  float* S    = (float*)(ws + 31657984);  // 8388608 (B*64*D*N*4)
  float* P    = (float*)(ws + 40046592);  // 8388608
  float* Hst  = (float*)(ws + 48435200);  // 8388608
  unsigned* bars = (unsigned*)(ws + 56823808); // 8 bytes

  hipLaunchKernelGGL(k_prep,   dim3(177),      dim3(256), 0, stream, xpw, dtw, Alog, te, w2T, dtwT, A2, sg, bars);
  hipLaunchKernelGGL(k_xz,     dim3(16, 3, 8), dim3(256), 0, stream, x, w2T, xzp);
  hipLaunchKernelGGL(k_reduce, dim3(384),      dim3(256), 0, stream, (const float4*)xzp, (float4*)xz);
  hipLaunchKernelGGL(k_fused,  dim3(64, 4, 2), dim3(256), 0, stream, x, xz, dtwT, dtb, A2, sg, Dpar, S, P, Hst, out, bars);
}

// Round 4
// 186.152 us; speedup vs baseline: 1.8487x; 1.4192x over previous
//
#include <hip/hip_runtime.h>
#include <math.h>

// SelectiveSSMBlock: B=2, L=2048, D=1024, N=16, R=64, fp32.
// R11: revert mega-fusion (software grid barriers cost ~50-65us each on
//     8-XCD gfx950 — abandoned). Back to R7 split structure, but delta is
//     recomputed INLINE in scan1/scan3 (same arithmetic as R10's P0, which
//     passed): del array + k_delta launch eliminated (-33.6 MB traffic,
//     -1 launch). 6 kernels: prep, xz, reduce, scan1f, scan2, scan3f.

#define LOG2E 1.44269504088896340736f
typedef float v2f __attribute__((ext_vector_type(2)));

__device__ __forceinline__ float fexp2(float v){
#if defined(__has_builtin)
#if __has_builtin(__builtin_amdgcn_exp2f)
  return __builtin_amdgcn_exp2f(v);
#else
  return exp2f(v);
#endif
#else
  return exp2f(v);
#endif
}

__device__ __forceinline__ float fsoftplus(float v){
  return fmaxf(v, 0.f) + __logf(1.f + __expf(-fabsf(v)));
}

// ---------------- prep
__global__ __launch_bounds__(256) void k_prep(const float* __restrict__ xpw,
                                              const float* __restrict__ dtw,
                                              const float* __restrict__ alog,
                                              const float* __restrict__ te,
                                              float* __restrict__ w2T,
                                              float* __restrict__ dtwT,
                                              float* __restrict__ A2,
                                              float* __restrict__ sg){
  __shared__ float sm[32 * 33];
  const int bid = blockIdx.x, t = threadIdx.x;
  const int lane = t & 31, srow = t >> 5;
  if (bid < 96){
    const int kt = bid / 3, ct = bid - kt * 3;
#pragma unroll
    for (int r = 0; r < 4; r++){
      const int cr = srow * 4 + r;
      sm[cr * 33 + lane] = xpw[(size_t)(ct * 32 + cr) * 1024 + kt * 32 + lane];
    }
    __syncthreads();
#pragma unroll
    for (int r = 0; r < 4; r++){
      const int kr = srow * 4 + r;
      const int kg = kt * 32 + kr;
      const float s = 1.f / (1.f + __expf(-te[kg]));
      w2T[(size_t)kg * 96 + ct * 32 + lane] = sm[lane * 33 + kr] * s;
    }
  } else if (bid < 160){
    const int idx = bid - 96, dti = idx >> 1, kt2 = idx & 1;
#pragma unroll
    for (int r = 0; r < 4; r++){
      const int cr = srow * 4 + r;
      sm[cr * 33 + lane] = dtw[(size_t)(dti * 32 + cr) * 64 + kt2 * 32 + lane];
    }
    __syncthreads();
#pragma unroll
    for (int r = 0; r < 4; r++){
      const int kr = srow * 4 + r;
      dtwT[(size_t)(kt2 * 32 + kr) * 1024 + dti * 32 + lane] = sm[lane * 33 + kr];
    }
  } else if (bid < 176){
    const int j = (bid - 160) * 1024 + t;
#pragma unroll
    for (int i = 0; i < 4; i++)
      A2[j + i * 256] = -__expf(alog[j + i * 256]) * LOG2E;
  } else {
#pragma unroll
    for (int i = 0; i < 4; i++){
      const int m = i * 256 + t;
      sg[m] = 1.f / (1.f + __expf(-te[m]));
    }
  }
}

// ---------------- xz partial GEMM, K-split 8 (KC=128). Grid (16,3,8)=384.
__global__ __launch_bounds__(256) void k_xz(const float* __restrict__ x,
                                            const float* __restrict__ w2T,
                                            float* __restrict__ xzp){
  __shared__ float xT[32 * 257];
  const int t = threadIdx.x;
  const int row0 = blockIdx.x * 256;
  const int c0 = blockIdx.y * 32;
  const int kbase = blockIdx.z * 128;
  v2f acc[16];
#pragma unroll
  for (int c = 0; c < 16; c++) acc[c] = (v2f){0.f, 0.f};
  const int kq = t & 7, rsub = t >> 3;
  for (int kt = 0; kt < 4; ++kt){
    const int k0 = kbase + kt * 32;
    __syncthreads();
#pragma unroll
    for (int p = 0; p < 8; p++){
      const int r = p * 32 + rsub;
      const float4 v = *reinterpret_cast<const float4*>(&x[(size_t)(row0 + r) * 1024 + k0 + kq * 4]);
      xT[(kq * 4 + 0) * 257 + r] = v.x;
      xT[(kq * 4 + 1) * 257 + r] = v.y;
      xT[(kq * 4 + 2) * 257 + r] = v.z;
      xT[(kq * 4 + 3) * 257 + r] = v.w;
    }
    __syncthreads();
#pragma unroll 4
    for (int kk = 0; kk < 32; ++kk){
      const float xv = xT[kk * 257 + t];
      const v2f xv2 = {xv, xv};
      const v2f* wr = reinterpret_cast<const v2f*>(&w2T[(size_t)(k0 + kk) * 96 + c0]);
#pragma unroll
      for (int c = 0; c < 16; c++) acc[c] = acc[c] + xv2 * wr[c];
    }
  }
  float4* o = reinterpret_cast<float4*>(xzp + ((size_t)blockIdx.z * 4096 + row0 + t) * 96 + c0);
  const float4* av = reinterpret_cast<const float4*>(acc);
#pragma unroll
  for (int q = 0; q < 8; q++) o[q] = av[q];
}

// ---------------- reduce 8 partials -> xz
__global__ __launch_bounds__(256) void k_reduce(const float4* __restrict__ p,
                                                float4* __restrict__ xz){
  const int i = blockIdx.x * 256 + threadIdx.x;
  float4 r = p[i];
#pragma unroll
  for (int s = 1; s < 8; s++){
    const float4 a = p[(size_t)s * 98304 + i];
    r.x += a.x; r.y += a.y; r.z += a.z; r.w += a.w;
  }
  xz[i] = r;
}

// ---------------- scan1 with inline delta. Grid (64,4,2).
__global__ __launch_bounds__(256) void k_scan1f(const float* __restrict__ x,
                                                const float* __restrict__ xz,
                                                const float* __restrict__ dtwT,
                                                const float* __restrict__ dtb,
                                                const float* __restrict__ A2,
                                                const float* __restrict__ sg,
                                                float* __restrict__ S,
                                                float* __restrict__ P){
  __shared__ float xzd[32 * 64];   // delta-part rows [l][k]  8 KB
  const int t = threadIdx.x;
  const int chunk = blockIdx.x, dgrp = blockIdx.y, b = blockIdx.z;
  const int d = dgrp * 256 + t;
  const int l0 = chunk * 32;
  const float* xzb = xz + (size_t)(b * 2048 + l0) * 96;
  const size_t xidx0 = (size_t)(b * 2048 + l0) * 1024 + d;

  // stage delta-part: 32 rows x 16 float4, 2 per thread
#pragma unroll
  for (int i = t; i < 512; i += 256){
    const int r = i >> 4, c4 = i & 15;
    const float4 v = *reinterpret_cast<const float4*>(xzb + r * 96 + c4 * 4);
    *reinterpret_cast<float4*>(&xzd[r * 64 + c4 * 4]) = v;
  }

  v2f wv[32];
#pragma unroll
  for (int k2 = 0; k2 < 32; k2++){
    wv[k2].x = dtwT[(size_t)(2 * k2) * 1024 + d];
    wv[k2].y = dtwT[(size_t)(2 * k2 + 1) * 1024 + d];
  }
  const float dtbv = dtb[d];
  const float sgv = sg[d];
  float xd[32];
#pragma unroll
  for (int li = 0; li < 32; ++li)
    xd[li] = x[xidx0 + (size_t)li * 1024] * sgv;

  float a2[16];
  {
    const float4* ap = reinterpret_cast<const float4*>(A2 + (size_t)d * 16);
#pragma unroll
    for (int q = 0; q < 4; q++){
      const float4 v = ap[q];
      a2[q*4] = v.x; a2[q*4+1] = v.y; a2[q*4+2] = v.z; a2[q*4+3] = v.w;
    }
  }
  bool uni = true;
#pragma unroll
  for (int n = 1; n < 16; n++) uni = uni && (a2[n] == a2[0]);

  __syncthreads();

  const size_t sbase = ((size_t)((b * 64 + chunk) * 1024 + d)) * 16;

  if (uni){
    const float a2u = a2[0];
    v2f h2[8];
#pragma unroll
    for (int q = 0; q < 8; q++) h2[q] = (v2f){0.f, 0.f};
    float sumd = 0.f;
#pragma unroll 4
    for (int li = 0; li < 32; ++li){
      // inline delta (same op order as R10 P0: float4 walk, two v2f FMAs)
      const float4* dp4 = reinterpret_cast<const float4*>(&xzd[li * 64]);
      v2f acc = {dtbv, 0.f};
#pragma unroll
      for (int k4 = 0; k4 < 16; k4++){
        const float4 xv = dp4[k4];
        acc = acc + (v2f){xv.x, xv.y} * wv[2 * k4];
        acc = acc + (v2f){xv.z, xv.w} * wv[2 * k4 + 1];
      }
      const float dl = fsoftplus(acc.x + acc.y);
      sumd += dl;
      const float tt = fexp2(dl * a2u);
      const float duv = dl * xd[li];
      const v2f tt2 = {tt, tt}, du2 = {duv, duv};
      const v2f* brow = reinterpret_cast<const v2f*>(xzb + li * 96 + 64);
#pragma unroll
      for (int q = 0; q < 8; q++) h2[q] = h2[q] * tt2 + brow[q] * du2;
    }
    const float4* hv = reinterpret_cast<const float4*>(h2);
#pragma unroll
    for (int q = 0; q < 4; q++)
      *reinterpret_cast<float4*>(&S[sbase + q * 4]) = hv[q];
    const float Ppu = fexp2(a2u * sumd);
    const float4 pv = {Ppu, Ppu, Ppu, Ppu};
#pragma unroll
    for (int q = 0; q < 4; q++)
      *reinterpret_cast<float4*>(&P[sbase + q * 4]) = pv;
  } else {
    float h[16], Pp[16];
#pragma unroll
    for (int n = 0; n < 16; n++){ h[n] = 0.f; Pp[n] = 1.f; }
    for (int li = 0; li < 32; ++li){
      const float4* dp4 = reinterpret_cast<const float4*>(&xzd[li * 64]);
      v2f acc = {dtbv, 0.f};
#pragma unroll
      for (int k4 = 0; k4 < 16; k4++){
        const float4 xv = dp4[k4];
        acc = acc + (v2f){xv.x, xv.y} * wv[2 * k4];
        acc = acc + (v2f){xv.z, xv.w} * wv[2 * k4 + 1];
      }
      const float dl = fsoftplus(acc.x + acc.y);
      const float duv = dl * xd[li];
      const float* brow = xzb + li * 96 + 64;
#pragma unroll
      for (int n = 0; n < 16; n++){
        const float tt = fexp2(dl * a2[n]);
        h[n] = fmaf(tt, h[n], duv * brow[n]);
        Pp[n] *= tt;
      }
    }
#pragma unroll
    for (int q = 0; q < 4; q++){
      float4 v; v.x = h[q*4]; v.y = h[q*4+1]; v.z = h[q*4+2]; v.w = h[q*4+3];
      *reinterpret_cast<float4*>(&S[sbase + q * 4]) = v;
      float4 u; u.x = Pp[q*4]; u.y = Pp[q*4+1]; u.z = Pp[q*4+2]; u.w = Pp[q*4+3];
      *reinterpret_cast<float4*>(&P[sbase + q * 4]) = u;
    }
  }
}

// ---------------- scan2: single-walk segmented combine, C=64. Grid 1024 x 256.
__global__ __launch_bounds__(256) void k_scan2(const float* __restrict__ S,
                                               const float* __restrict__ P,
                                               float* __restrict__ H){
  __shared__ float ls[256], lp[256];
  const int t = threadIdx.x;
  const int dn = t & 31, seg = t >> 5;
  const int n = dn & 15, dloc = dn >> 4;
  const int bid = blockIdx.x;
  const int b = bid >> 9, dpair = bid & 511;
  const int d = dpair * 2 + dloc;
  const size_t sbase = ((size_t)(b * 64) * 1024 + d) * 16 + n;  // + c*16384
  float Sv[8], Pv[8];
  float s = 0.f, p = 1.f;
#pragma unroll
  for (int i = 0; i < 8; i++){
    const size_t idx = sbase + (size_t)(seg * 8 + i) * 16384;
    Sv[i] = S[idx]; Pv[i] = P[idx];
    s = fmaf(Pv[i], s, Sv[i]);
    p *= Pv[i];
  }
  ls[t] = s; lp[t] = p;
  __syncthreads();
  float h = 0.f;
  for (int j = 0; j < seg; j++)
    h = fmaf(lp[j * 32 + dn], h, ls[j * 32 + dn]);
#pragma unroll
  for (int i = 0; i < 8; i++){
    const size_t idx = sbase + (size_t)(seg * 8 + i) * 16384;
    H[idx] = h;
    h = fmaf(Pv[i], h, Sv[i]);
  }
}

// ---------------- scan3 with inline delta + true init + y. Grid (64,4,2).
__global__ __launch_bounds__(256) void k_scan3f(const float* __restrict__ x,
                                                const float* __restrict__ xz,
                                                const float* __restrict__ dtwT,
                                                const float* __restrict__ dtb,
                                                const float* __restrict__ A2,
                                                const float* __restrict__ sg,
                                                const float* __restrict__ Dpar,
                                                const float* __restrict__ H,
                                                float* __restrict__ out){
  __shared__ float xzd[32 * 64];   // delta-part rows [l][k]  8 KB
  const int t = threadIdx.x;
  const int chunk = blockIdx.x, dgrp = blockIdx.y, b = blockIdx.z;
  const int d = dgrp * 256 + t;
  const int l0 = chunk * 32;
  const float* xzb = xz + (size_t)(b * 2048 + l0) * 96;
  const size_t xidx0 = (size_t)(b * 2048 + l0) * 1024 + d;

#pragma unroll
  for (int i = t; i < 512; i += 256){
    const int r = i >> 4, c4 = i & 15;
    const float4 v = *reinterpret_cast<const float4*>(xzb + r * 96 + c4 * 4);
    *reinterpret_cast<float4*>(&xzd[r * 64 + c4 * 4]) = v;
  }

  v2f wv[32];
#pragma unroll
  for (int k2 = 0; k2 < 32; k2++){
    wv[k2].x = dtwT[(size_t)(2 * k2) * 1024 + d];
    wv[k2].y = dtwT[(size_t)(2 * k2 + 1) * 1024 + d];
  }
  const float dtbv = dtb[d];
  const float sgv = sg[d];
  float xd[32];
#pragma unroll
  for (int li = 0; li < 32; ++li)
    xd[li] = x[xidx0 + (size_t)li * 1024] * sgv;

  float a2[16];
  {
    const float4* ap = reinterpret_cast<const float4*>(A2 + (size_t)d * 16);
#pragma unroll
    for (int q = 0; q < 4; q++){
      const float4 v = ap[q];
      a2[q*4] = v.x; a2[q*4+1] = v.y; a2[q*4+2] = v.z; a2[q*4+3] = v.w;
    }
  }
  bool uni = true;
#pragma unroll
  for (int n = 1; n < 16; n++) uni = uni && (a2[n] == a2[0]);

  __syncthreads();

  const float Dv = Dpar[d];
  const size_t hbase = ((size_t)((b * 64 + chunk) * 1024 + d)) * 16;

  if (uni){
    const float a2u = a2[0];
    v2f h2[8];
    {
      const float4* hp = reinterpret_cast<const float4*>(H + hbase);
      float4* hd = reinterpret_cast<float4*>(h2);
#pragma unroll
      for (int q = 0; q < 4; q++) hd[q] = hp[q];
    }
#pragma unroll 4
    for (int li = 0; li < 32; ++li){
      const float4* dp4 = reinterpret_cast<const float4*>(&xzd[li * 64]);
      v2f acc = {dtbv, 0.f};
#pragma unroll
      for (int k4 = 0; k4 < 16; k4++){
        const float4 xv = dp4[k4];
        acc = acc + (v2f){xv.x, xv.y} * wv[2 * k4];
        acc = acc + (v2f){xv.z, xv.w} * wv[2 * k4 + 1];
      }
      const float dl = fsoftplus(acc.x + acc.y);
      const float tt = fexp2(dl * a2u);
      const float duv = dl * xd[li];
      const v2f tt2 = {tt, tt}, du2 = {duv, duv};
      const v2f* brow = reinterpret_cast<const v2f*>(xzb + li * 96 + 64);
      const v2f* crow = reinterpret_cast<const v2f*>(xzb + li * 96 + 80);
      v2f yv = {0.f, 0.f};
#pragma unroll
      for (int q = 0; q < 8; q++){
        h2[q] = h2[q] * tt2 + brow[q] * du2;
        yv = yv + h2[q] * crow[q];
      }
      out[xidx0 + (size_t)li * 1024] = fmaf(xd[li], Dv, yv.x + yv.y);
    }
  } else {
    float h[16];
    {
      const float4* hp = reinterpret_cast<const float4*>(H + hbase);
#pragma unroll
      for (int q = 0; q < 4; q++){
        const float4 v = hp[q];
        h[q*4] = v.x; h[q*4+1] = v.y; h[q*4+2] = v.z; h[q*4+3] = v.w;
      }
    }
    for (int li = 0; li < 32; ++li){
      const float4* dp4 = reinterpret_cast<const float4*>(&xzd[li * 64]);
      v2f acc = {dtbv, 0.f};
#pragma unroll
      for (int k4 = 0; k4 < 16; k4++){
        const float4 xv = dp4[k4];
        acc = acc + (v2f){xv.x, xv.y} * wv[2 * k4];
        acc = acc + (v2f){xv.z, xv.w} * wv[2 * k4 + 1];
      }
      const float dl = fsoftplus(acc.x + acc.y);
      const float duv = dl * xd[li];
      const float* brow = xzb + li * 96 + 64;
      float y = 0.f;
#pragma unroll
      for (int n = 0; n < 16; n++){
        const float tt = fexp2(dl * a2[n]);
        h[n] = fmaf(tt, h[n], duv * brow[n]);
        y = fmaf(h[n], brow[16 + n], y);
      }
      out[xidx0 + (size_t)li * 1024] = fmaf(xd[li], Dv, y);
    }
  }
}

extern "C" void kernel_launch(void* const* d_in, const int* in_sizes, int n_in,
                              void* d_out, int out_size, void* d_ws, size_t ws_size,
                              hipStream_t stream){
  const float* x    = (const float*)d_in[0];
  const float* Alog = (const float*)d_in[1];
  const float* xpw  = (const float*)d_in[2];
  const float* dtw  = (const float*)d_in[3];
  const float* dtb  = (const float*)d_in[4];
  const float* Dpar = (const float*)d_in[5];
  const float* te   = (const float*)d_in[6];
  float* out = (float*)d_out;
  char* ws = (char*)d_ws;

  float* w2T  = (float*)(ws);             // 393216
  float* A2   = (float*)(ws + 393216);    // 65536
  float* sg   = (float*)(ws + 458752);    // 4096
  float* dtwT = (float*)(ws + 462848);    // 262144
  float* xz   = (float*)(ws + 724992);    // 1572864 -> ends 2297856
  float* xzp  = (float*)(ws + 2297856);   // 12582912 -> ends 14880768
  float* S    = (float*)(ws + 14880768);  // 8388608
  float* P    = (float*)(ws + 23269376);  // 8388608
  float* Hst  = (float*)(ws + 31657984);  // 8388608 -> ends 40046592

  hipLaunchKernelGGL(k_prep,   dim3(177),      dim3(256), 0, stream, xpw, dtw, Alog, te, w2T, dtwT, A2, sg);
  hipLaunchKernelGGL(k_xz,     dim3(16, 3, 8), dim3(256), 0, stream, x, w2T, xzp);
  hipLaunchKernelGGL(k_reduce, dim3(384),      dim3(256), 0, stream, (const float4*)xzp, (float4*)xz);
  hipLaunchKernelGGL(k_scan1f, dim3(64, 4, 2), dim3(256), 0, stream, x, xz, dtwT, dtb, A2, sg, S, P);
  hipLaunchKernelGGL(k_scan2,  dim3(1024),     dim3(256), 0, stream, S, P, Hst);
  hipLaunchKernelGGL(k_scan3f, dim3(64, 4, 2), dim3(256), 0, stream, x, xz, dtwT, dtb, A2, sg, Dpar, Hst, out);
}

// Round 5
// 165.033 us; speedup vs baseline: 2.0853x; 1.1280x over previous
//
#include <hip/hip_runtime.h>
#include <math.h>

// SelectiveSSMBlock: B=2, L=2048, D=1024, N=16, R=64, fp32.
// R12: R7 structure restored (del materialized — inline delta in scans
//     regressed: serial GEMM chain inside latency-bound scans). Occupancy
//     fixes only:
//     - k_xz K-split 8->16 (KC=64): 384 blocks (1.5/CU, imbalanced) -> 768
//       (3/CU exact). Partials 25.2 MB (ws is ~268 MB per fill counters).
//     - scans C=64->128 (len 16): 512 blocks (2/CU) -> 1024 (4/CU), serial
//       chain halved. Per-thread code identical to R7, loop count halved.

#define LOG2E 1.44269504088896340736f
typedef float v2f __attribute__((ext_vector_type(2)));

__device__ __forceinline__ float fexp2(float v){
#if defined(__has_builtin)
#if __has_builtin(__builtin_amdgcn_exp2f)
  return __builtin_amdgcn_exp2f(v);
#else
  return exp2f(v);
#endif
#else
  return exp2f(v);
#endif
}

__device__ __forceinline__ float fsoftplus(float v){
  return fmaxf(v, 0.f) + __logf(1.f + __expf(-fabsf(v)));
}

// ---------------- prep (unchanged)
__global__ __launch_bounds__(256) void k_prep(const float* __restrict__ xpw,
                                              const float* __restrict__ dtw,
                                              const float* __restrict__ alog,
                                              const float* __restrict__ te,
                                              float* __restrict__ w2T,
                                              float* __restrict__ dtwT,
                                              float* __restrict__ A2,
                                              float* __restrict__ sg){
  __shared__ float sm[32 * 33];
  const int bid = blockIdx.x, t = threadIdx.x;
  const int lane = t & 31, srow = t >> 5;
  if (bid < 96){
    const int kt = bid / 3, ct = bid - kt * 3;
#pragma unroll
    for (int r = 0; r < 4; r++){
      const int cr = srow * 4 + r;
      sm[cr * 33 + lane] = xpw[(size_t)(ct * 32 + cr) * 1024 + kt * 32 + lane];
    }
    __syncthreads();
#pragma unroll
    for (int r = 0; r < 4; r++){
      const int kr = srow * 4 + r;
      const int kg = kt * 32 + kr;
      const float s = 1.f / (1.f + __expf(-te[kg]));
      w2T[(size_t)kg * 96 + ct * 32 + lane] = sm[lane * 33 + kr] * s;
    }
  } else if (bid < 160){
    const int idx = bid - 96, dti = idx >> 1, kt2 = idx & 1;
#pragma unroll
    for (int r = 0; r < 4; r++){
      const int cr = srow * 4 + r;
      sm[cr * 33 + lane] = dtw[(size_t)(dti * 32 + cr) * 64 + kt2 * 32 + lane];
    }
    __syncthreads();
#pragma unroll
    for (int r = 0; r < 4; r++){
      const int kr = srow * 4 + r;
      dtwT[(size_t)(kt2 * 32 + kr) * 1024 + dti * 32 + lane] = sm[lane * 33 + kr];
    }
  } else if (bid < 176){
    const int j = (bid - 160) * 1024 + t;
#pragma unroll
    for (int i = 0; i < 4; i++)
      A2[j + i * 256] = -__expf(alog[j + i * 256]) * LOG2E;
  } else {
#pragma unroll
    for (int i = 0; i < 4; i++){
      const int m = i * 256 + t;
      sg[m] = 1.f / (1.f + __expf(-te[m]));
    }
  }
}

// ---------------- xz partial GEMM, K-split 16 (KC=64). Grid (16,3,16)=768.
__global__ __launch_bounds__(256) void k_xz(const float* __restrict__ x,
                                            const float* __restrict__ w2T,
                                            float* __restrict__ xzp){
  __shared__ float xT[32 * 257];
  const int t = threadIdx.x;
  const int row0 = blockIdx.x * 256;
  const int c0 = blockIdx.y * 32;
  const int kbase = blockIdx.z * 64;
  v2f acc[16];
#pragma unroll
  for (int c = 0; c < 16; c++) acc[c] = (v2f){0.f, 0.f};
  const int kq = t & 7, rsub = t >> 3;
  for (int kt = 0; kt < 2; ++kt){
    const int k0 = kbase + kt * 32;
    __syncthreads();
#pragma unroll
    for (int p = 0; p < 8; p++){
      const int r = p * 32 + rsub;
      const float4 v = *reinterpret_cast<const float4*>(&x[(size_t)(row0 + r) * 1024 + k0 + kq * 4]);
      xT[(kq * 4 + 0) * 257 + r] = v.x;
      xT[(kq * 4 + 1) * 257 + r] = v.y;
      xT[(kq * 4 + 2) * 257 + r] = v.z;
      xT[(kq * 4 + 3) * 257 + r] = v.w;
    }
    __syncthreads();
#pragma unroll 4
    for (int kk = 0; kk < 32; ++kk){
      const float xv = xT[kk * 257 + t];
      const v2f xv2 = {xv, xv};
      const v2f* wr = reinterpret_cast<const v2f*>(&w2T[(size_t)(k0 + kk) * 96 + c0]);
#pragma unroll
      for (int c = 0; c < 16; c++) acc[c] = acc[c] + xv2 * wr[c];
    }
  }
  float4* o = reinterpret_cast<float4*>(xzp + ((size_t)blockIdx.z * 4096 + row0 + t) * 96 + c0);
  const float4* av = reinterpret_cast<const float4*>(acc);
#pragma unroll
  for (int q = 0; q < 8; q++) o[q] = av[q];
}

// ---------------- reduce 16 partials -> xz
__global__ __launch_bounds__(256) void k_reduce(const float4* __restrict__ p,
                                                float4* __restrict__ xz){
  const int i = blockIdx.x * 256 + threadIdx.x;
  float4 r = p[i];
#pragma unroll
  for (int s = 1; s < 16; s++){
    const float4 a = p[(size_t)s * 98304 + i];
    r.x += a.x; r.y += a.y; r.z += a.z; r.w += a.w;
  }
  xz[i] = r;
}

// ---------------- delta = softplus(xz[:, :64] @ dtwT + dtb). Grid (256,4).
__global__ __launch_bounds__(256) void k_delta(const float* __restrict__ xz,
                                               const float* __restrict__ dtwT,
                                               const float* __restrict__ dtb,
                                               float* __restrict__ del){
  const int t = threadIdx.x;
  const int r0 = blockIdx.x * 16;
  const int d = blockIdx.y * 256 + t;
  v2f wv[32];
#pragma unroll
  for (int k2 = 0; k2 < 32; k2++){
    wv[k2].x = dtwT[(size_t)(2 * k2) * 1024 + d];
    wv[k2].y = dtwT[(size_t)(2 * k2 + 1) * 1024 + d];
  }
  const float dtbv = dtb[d];
  const float* xzb = xz + (size_t)r0 * 96;
#pragma unroll 4
  for (int li = 0; li < 16; ++li){
    v2f acc = {dtbv, 0.f};
    const v2f* dp = reinterpret_cast<const v2f*>(xzb + li * 96);  // uniform -> s_load
#pragma unroll
    for (int k2 = 0; k2 < 32; k2++) acc = acc + dp[k2] * wv[k2];
    del[(size_t)(r0 + li) * 1024 + d] = fsoftplus(acc.x + acc.y);
  }
}

// ---------------- scan1: lean local scan, C=128, len=16. Grid (128,4,2).
__global__ __launch_bounds__(256) void k_scan1(const float* __restrict__ x,
                                               const float* __restrict__ del,
                                               const float* __restrict__ xz,
                                               const float* __restrict__ A2,
                                               const float* __restrict__ sg,
                                               float* __restrict__ S,
                                               float* __restrict__ P){
  const int t = threadIdx.x;
  const int chunk = blockIdx.x, dgrp = blockIdx.y, b = blockIdx.z;
  const int d = dgrp * 256 + t;
  const int l0 = chunk * 16;
  float a2[16];
  {
    const float4* ap = reinterpret_cast<const float4*>(A2 + (size_t)d * 16);
#pragma unroll
    for (int q = 0; q < 4; q++){
      const float4 v = ap[q];
      a2[q*4] = v.x; a2[q*4+1] = v.y; a2[q*4+2] = v.z; a2[q*4+3] = v.w;
    }
  }
  bool uni = true;
#pragma unroll
  for (int n = 1; n < 16; n++) uni = uni && (a2[n] == a2[0]);
  const float sgv = sg[d];
  const size_t xidx0 = (size_t)(b * 2048 + l0) * 1024 + d;
  const float* xzb = xz + (size_t)(b * 2048 + l0) * 96;
  const size_t base = ((size_t)((b * 128 + chunk) * 1024 + d)) * 16;
  if (uni){
    const float a2u = a2[0];
    v2f h2[8];
#pragma unroll
    for (int q = 0; q < 8; q++) h2[q] = (v2f){0.f, 0.f};
    float sumd = 0.f;
    float dl[16], du[16];
#pragma unroll
    for (int li = 0; li < 16; ++li){
      dl[li] = del[xidx0 + (size_t)li * 1024];
      du[li] = dl[li] * x[xidx0 + (size_t)li * 1024] * sgv;
    }
#pragma unroll 4
    for (int li = 0; li < 16; ++li){
      sumd += dl[li];
      const float tt = fexp2(dl[li] * a2u);
      const v2f tt2 = {tt, tt}, du2 = {du[li], du[li]};
      const v2f* brow = reinterpret_cast<const v2f*>(xzb + li * 96 + 64);
#pragma unroll
      for (int q = 0; q < 8; q++) h2[q] = h2[q] * tt2 + brow[q] * du2;
    }
    const float4* hv = reinterpret_cast<const float4*>(h2);
#pragma unroll
    for (int q = 0; q < 4; q++)
      *reinterpret_cast<float4*>(&S[base + q * 4]) = hv[q];
    const float Ppu = fexp2(a2u * sumd);
    const float4 pv = {Ppu, Ppu, Ppu, Ppu};
#pragma unroll
    for (int q = 0; q < 4; q++)
      *reinterpret_cast<float4*>(&P[base + q * 4]) = pv;
  } else {
    float h[16], Pp[16];
#pragma unroll
    for (int n = 0; n < 16; n++){ h[n] = 0.f; Pp[n] = 1.f; }
    for (int li = 0; li < 16; ++li){
      const float dv = del[xidx0 + (size_t)li * 1024];
      const float duv = dv * x[xidx0 + (size_t)li * 1024] * sgv;
      const float* brow = xzb + li * 96 + 64;
#pragma unroll
      for (int n = 0; n < 16; n++){
        const float tt = fexp2(dv * a2[n]);
        h[n] = fmaf(tt, h[n], duv * brow[n]);
        Pp[n] *= tt;
      }
    }
#pragma unroll
    for (int q = 0; q < 4; q++){
      float4 v; v.x = h[q*4]; v.y = h[q*4+1]; v.z = h[q*4+2]; v.w = h[q*4+3];
      *reinterpret_cast<float4*>(&S[base + q * 4]) = v;
      float4 u; u.x = Pp[q*4]; u.y = Pp[q*4+1]; u.z = Pp[q*4+2]; u.w = Pp[q*4+3];
      *reinterpret_cast<float4*>(&P[base + q * 4]) = u;
    }
  }
}

// ---------------- scan2: single-walk segmented combine, C=128. Grid 1024 x 256.
// Thread (dn, seg): 32 (d,n) x 8 segments of 16 chunks; S/P kept in registers.
__global__ __launch_bounds__(256) void k_scan2(const float* __restrict__ S,
                                               const float* __restrict__ P,
                                               float* __restrict__ H){
  __shared__ float ls[256], lp[256];
  const int t = threadIdx.x;
  const int dn = t & 31, seg = t >> 5;
  const int n = dn & 15, dloc = dn >> 4;
  const int bid = blockIdx.x;
  const int b = bid >> 9, dpair = bid & 511;
  const int d = dpair * 2 + dloc;
  const size_t sbase = ((size_t)(b * 128) * 1024 + d) * 16 + n;  // + c*16384
  float Sv[16], Pv[16];
  float s = 0.f, p = 1.f;
#pragma unroll
  for (int i = 0; i < 16; i++){
    const size_t idx = sbase + (size_t)(seg * 16 + i) * 16384;
    Sv[i] = S[idx]; Pv[i] = P[idx];
    s = fmaf(Pv[i], s, Sv[i]);
    p *= Pv[i];
  }
  ls[t] = s; lp[t] = p;
  __syncthreads();
  float h = 0.f;
  for (int j = 0; j < seg; j++)
    h = fmaf(lp[j * 32 + dn], h, ls[j * 32 + dn]);
#pragma unroll
  for (int i = 0; i < 16; i++){
    const size_t idx = sbase + (size_t)(seg * 16 + i) * 16384;
    H[idx] = h;
    h = fmaf(Pv[i], h, Sv[i]);
  }
}

// ---------------- scan3: lean scan with true init + y, C=128, len=16.
__global__ __launch_bounds__(256) void k_scan3(const float* __restrict__ x,
                                               const float* __restrict__ del,
                                               const float* __restrict__ xz,
                                               const float* __restrict__ A2,
                                               const float* __restrict__ sg,
                                               const float* __restrict__ Dpar,
                                               const float* __restrict__ H,
                                               float* __restrict__ out){
  const int t = threadIdx.x;
  const int chunk = blockIdx.x, dgrp = blockIdx.y, b = blockIdx.z;
  const int d = dgrp * 256 + t;
  const int l0 = chunk * 16;
  float a2[16];
  {
    const float4* ap = reinterpret_cast<const float4*>(A2 + (size_t)d * 16);
#pragma unroll
    for (int q = 0; q < 4; q++){
      const float4 v = ap[q];
      a2[q*4] = v.x; a2[q*4+1] = v.y; a2[q*4+2] = v.z; a2[q*4+3] = v.w;
    }
  }
  bool uni = true;
#pragma unroll
  for (int n = 1; n < 16; n++) uni = uni && (a2[n] == a2[0]);
  const float sgv = sg[d], Dv = Dpar[d];
  const size_t xidx0 = (size_t)(b * 2048 + l0) * 1024 + d;
  const float* xzb = xz + (size_t)(b * 2048 + l0) * 96;
  const size_t hbase = ((size_t)((b * 128 + chunk) * 1024 + d)) * 16;
  if (uni){
    const float a2u = a2[0];
    v2f h2[8];
    {
      const float4* hp = reinterpret_cast<const float4*>(H + hbase);
      float4* hd = reinterpret_cast<float4*>(h2);
#pragma unroll
      for (int q = 0; q < 4; q++) hd[q] = hp[q];
    }
    float dl[16], xd[16];
#pragma unroll
    for (int li = 0; li < 16; ++li){
      dl[li] = del[xidx0 + (size_t)li * 1024];
      xd[li] = x[xidx0 + (size_t)li * 1024] * sgv;
    }
#pragma unroll 4
    for (int li = 0; li < 16; ++li){
      const float duv = dl[li] * xd[li];
      const float tt = fexp2(dl[li] * a2u);
      const v2f tt2 = {tt, tt}, du2 = {duv, duv};
      const v2f* brow = reinterpret_cast<const v2f*>(xzb + li * 96 + 64);
      const v2f* crow = reinterpret_cast<const v2f*>(xzb + li * 96 + 80);
      v2f yv = {0.f, 0.f};
#pragma unroll
      for (int q = 0; q < 8; q++){
        h2[q] = h2[q] * tt2 + brow[q] * du2;
        yv = yv + h2[q] * crow[q];
      }
      out[xidx0 + (size_t)li * 1024] = fmaf(xd[li], Dv, yv.x + yv.y);
    }
  } else {
    float h[16];
    {
      const float4* hp = reinterpret_cast<const float4*>(H + hbase);
#pragma unroll
      for (int q = 0; q < 4; q++){
        const float4 v = hp[q];
        h[q*4] = v.x; h[q*4+1] = v.y; h[q*4+2] = v.z; h[q*4+3] = v.w;
      }
    }
    for (int li = 0; li < 16; ++li){
      const float dv = del[xidx0 + (size_t)li * 1024];
      const float xdv = x[xidx0 + (size_t)li * 1024] * sgv;
      const float duv = dv * xdv;
      const float* brow = xzb + li * 96 + 64;
      float y = 0.f;
#pragma unroll
      for (int n = 0; n < 16; n++){
        const float tt = fexp2(dv * a2[n]);
        h[n] = fmaf(tt, h[n], duv * brow[n]);
        y = fmaf(h[n], brow[16 + n], y);
      }
      out[xidx0 + (size_t)li * 1024] = fmaf(xdv, Dv, y);
    }
  }
}

extern "C" void kernel_launch(void* const* d_in, const int* in_sizes, int n_in,
                              void* d_out, int out_size, void* d_ws, size_t ws_size,
                              hipStream_t stream){
  const float* x    = (const float*)d_in[0];
  const float* Alog = (const float*)d_in[1];
  const float* xpw  = (const float*)d_in[2];
  const float* dtw  = (const float*)d_in[3];
  const float* dtb  = (const float*)d_in[4];
  const float* Dpar = (const float*)d_in[5];
  const float* te   = (const float*)d_in[6];
  float* out = (float*)d_out;
  char* ws = (char*)d_ws;

  float* w2T  = (float*)(ws);             // 393216
  float* A2   = (float*)(ws + 393216);    // 65536
  float* sg   = (float*)(ws + 458752);    // 4096
  float* dtwT = (float*)(ws + 462848);    // 262144
  float* xz   = (float*)(ws + 724992);    // 1572864 -> 2297856
  float* del  = (float*)(ws + 2297856);   // 16777216 -> 19075072
  float* xzp  = (float*)(ws + 19075072);  // 25165824 (16 partials) -> 44240896
  float* S    = (float*)(ws + 44240896);  // 16777216 (B*128*D*N*4) -> 61018112
  float* P    = (float*)(ws + 61018112);  // 16777216 -> 77795328
  float* Hst  = (float*)(ws + 77795328);  // 16777216 -> 94572544

  hipLaunchKernelGGL(k_prep,   dim3(177),       dim3(256), 0, stream, xpw, dtw, Alog, te, w2T, dtwT, A2, sg);
  hipLaunchKernelGGL(k_xz,     dim3(16, 3, 16), dim3(256), 0, stream, x, w2T, xzp);
  hipLaunchKernelGGL(k_reduce, dim3(384),       dim3(256), 0, stream, (const float4*)xzp, (float4*)xz);
  hipLaunchKernelGGL(k_delta,  dim3(256, 4),    dim3(256), 0, stream, xz, dtwT, dtb, del);
  hipLaunchKernelGGL(k_scan1,  dim3(128, 4, 2), dim3(256), 0, stream, x, del, xz, A2, sg, S, P);
  hipLaunchKernelGGL(k_scan2,  dim3(1024),      dim3(256), 0, stream, S, P, Hst);
  hipLaunchKernelGGL(k_scan3,  dim3(128, 4, 2), dim3(256), 0, stream, x, del, xz, A2, sg, Dpar, Hst, out);
}

// Round 6
// 152.450 us; speedup vs baseline: 2.2574x; 1.0825x over previous
//
#include <hip/hip_runtime.h>
#include <math.h>

// SelectiveSSMBlock: B=2, L=2048, D=1024, N=16, R=64, fp32.
// R13: R7 structure exactly (best measured: 160.6us), plus one targeted
//     latency fix: scan1/scan3 stage the block-uniform xz B/C row slices
//     into LDS (coalesced loads + broadcast reads) instead of s_load
//     chains (32 floats/row x 32 rows > SGPR budget -> partially serial
//     ~200cyc scalar-cache misses, unhidden at 2 blocks/CU).
//     Arithmetic order identical -> bitwise-same results.
// Known cost model (R8/R10/R12 cross-check): measured dur includes ~86us
//     of harness ws re-poison fills (2x43us, fixed); our kernels ~74us;
//     intermediates are L3-resident -> scans latency-bound, not BW-bound.

#define LOG2E 1.44269504088896340736f
typedef float v2f __attribute__((ext_vector_type(2)));

__device__ __forceinline__ float fexp2(float v){
#if defined(__has_builtin)
#if __has_builtin(__builtin_amdgcn_exp2f)
  return __builtin_amdgcn_exp2f(v);
#else
  return exp2f(v);
#endif
#else
  return exp2f(v);
#endif
}

__device__ __forceinline__ float fsoftplus(float v){
  return fmaxf(v, 0.f) + __logf(1.f + __expf(-fabsf(v)));
}

// ---------------- prep (unchanged)
__global__ __launch_bounds__(256) void k_prep(const float* __restrict__ xpw,
                                              const float* __restrict__ dtw,
                                              const float* __restrict__ alog,
                                              const float* __restrict__ te,
                                              float* __restrict__ w2T,
                                              float* __restrict__ dtwT,
                                              float* __restrict__ A2,
                                              float* __restrict__ sg){
  __shared__ float sm[32 * 33];
  const int bid = blockIdx.x, t = threadIdx.x;
  const int lane = t & 31, srow = t >> 5;
  if (bid < 96){
    const int kt = bid / 3, ct = bid - kt * 3;
#pragma unroll
    for (int r = 0; r < 4; r++){
      const int cr = srow * 4 + r;
      sm[cr * 33 + lane] = xpw[(size_t)(ct * 32 + cr) * 1024 + kt * 32 + lane];
    }
    __syncthreads();
#pragma unroll
    for (int r = 0; r < 4; r++){
      const int kr = srow * 4 + r;
      const int kg = kt * 32 + kr;
      const float s = 1.f / (1.f + __expf(-te[kg]));
      w2T[(size_t)kg * 96 + ct * 32 + lane] = sm[lane * 33 + kr] * s;
    }
  } else if (bid < 160){
    const int idx = bid - 96, dti = idx >> 1, kt2 = idx & 1;
#pragma unroll
    for (int r = 0; r < 4; r++){
      const int cr = srow * 4 + r;
      sm[cr * 33 + lane] = dtw[(size_t)(dti * 32 + cr) * 64 + kt2 * 32 + lane];
    }
    __syncthreads();
#pragma unroll
    for (int r = 0; r < 4; r++){
      const int kr = srow * 4 + r;
      dtwT[(size_t)(kt2 * 32 + kr) * 1024 + dti * 32 + lane] = sm[lane * 33 + kr];
    }
  } else if (bid < 176){
    const int j = (bid - 160) * 1024 + t;
#pragma unroll
    for (int i = 0; i < 4; i++)
      A2[j + i * 256] = -__expf(alog[j + i * 256]) * LOG2E;
  } else {
#pragma unroll
    for (int i = 0; i < 4; i++){
      const int m = i * 256 + t;
      sg[m] = 1.f / (1.f + __expf(-te[m]));
    }
  }
}

// ---------------- xz partial GEMM, K-split 8 (KC=128). Grid (16,3,8)=384.
__global__ __launch_bounds__(256) void k_xz(const float* __restrict__ x,
                                            const float* __restrict__ w2T,
                                            float* __restrict__ xzp){
  __shared__ float xT[32 * 257];
  const int t = threadIdx.x;
  const int row0 = blockIdx.x * 256;
  const int c0 = blockIdx.y * 32;
  const int kbase = blockIdx.z * 128;
  v2f acc[16];
#pragma unroll
  for (int c = 0; c < 16; c++) acc[c] = (v2f){0.f, 0.f};
  const int kq = t & 7, rsub = t >> 3;
  for (int kt = 0; kt < 4; ++kt){
    const int k0 = kbase + kt * 32;
    __syncthreads();
#pragma unroll
    for (int p = 0; p < 8; p++){
      const int r = p * 32 + rsub;
      const float4 v = *reinterpret_cast<const float4*>(&x[(size_t)(row0 + r) * 1024 + k0 + kq * 4]);
      xT[(kq * 4 + 0) * 257 + r] = v.x;
      xT[(kq * 4 + 1) * 257 + r] = v.y;
      xT[(kq * 4 + 2) * 257 + r] = v.z;
      xT[(kq * 4 + 3) * 257 + r] = v.w;
    }
    __syncthreads();
#pragma unroll 4
    for (int kk = 0; kk < 32; ++kk){
      const float xv = xT[kk * 257 + t];
      const v2f xv2 = {xv, xv};
      const v2f* wr = reinterpret_cast<const v2f*>(&w2T[(size_t)(k0 + kk) * 96 + c0]);
#pragma unroll
      for (int c = 0; c < 16; c++) acc[c] = acc[c] + xv2 * wr[c];
    }
  }
  float4* o = reinterpret_cast<float4*>(xzp + ((size_t)blockIdx.z * 4096 + row0 + t) * 96 + c0);
  const float4* av = reinterpret_cast<const float4*>(acc);
#pragma unroll
  for (int q = 0; q < 8; q++) o[q] = av[q];
}

// ---------------- reduce 8 partials -> xz
__global__ __launch_bounds__(256) void k_reduce(const float4* __restrict__ p,
                                                float4* __restrict__ xz){
  const int i = blockIdx.x * 256 + threadIdx.x;
  float4 r = p[i];
#pragma unroll
  for (int s = 1; s < 8; s++){
    const float4 a = p[(size_t)s * 98304 + i];
    r.x += a.x; r.y += a.y; r.z += a.z; r.w += a.w;
  }
  xz[i] = r;
}

// ---------------- delta = softplus(xz[:, :64] @ dtwT + dtb). Grid (256,4).
__global__ __launch_bounds__(256) void k_delta(const float* __restrict__ xz,
                                               const float* __restrict__ dtwT,
                                               const float* __restrict__ dtb,
                                               float* __restrict__ del){
  const int t = threadIdx.x;
  const int r0 = blockIdx.x * 16;
  const int d = blockIdx.y * 256 + t;
  v2f wv[32];
#pragma unroll
  for (int k2 = 0; k2 < 32; k2++){
    wv[k2].x = dtwT[(size_t)(2 * k2) * 1024 + d];
    wv[k2].y = dtwT[(size_t)(2 * k2 + 1) * 1024 + d];
  }
  const float dtbv = dtb[d];
  const float* xzb = xz + (size_t)r0 * 96;
#pragma unroll 4
  for (int li = 0; li < 16; ++li){
    v2f acc = {dtbv, 0.f};
    const v2f* dp = reinterpret_cast<const v2f*>(xzb + li * 96);  // uniform -> s_load
#pragma unroll
    for (int k2 = 0; k2 < 32; k2++) acc = acc + dp[k2] * wv[k2];
    del[(size_t)(r0 + li) * 1024 + d] = fsoftplus(acc.x + acc.y);
  }
}

// ---------------- scan1: lean local scan, C=64, len=32 (two 16-step phases).
// B rows staged in LDS (broadcast reads) instead of s_load chains.
__global__ __launch_bounds__(256) void k_scan1(const float* __restrict__ x,
                                               const float* __restrict__ del,
                                               const float* __restrict__ xz,
                                               const float* __restrict__ A2,
                                               const float* __restrict__ sg,
                                               float* __restrict__ S,
                                               float* __restrict__ P){
  __shared__ float bsm[32 * 16];   // B rows [l][n]  2 KB
  const int t = threadIdx.x;
  const int chunk = blockIdx.x, dgrp = blockIdx.y, b = blockIdx.z;
  const int d = dgrp * 256 + t;
  const int l0 = chunk * 32;
  const float* xzb = xz + (size_t)(b * 2048 + l0) * 96;

  // stage B slice: 32 rows x 4 float4 = 128 float4, threads 0..127
  if (t < 128){
    const int r = t >> 2, c4 = t & 3;
    *reinterpret_cast<float4*>(&bsm[r * 16 + c4 * 4]) =
      *reinterpret_cast<const float4*>(xzb + r * 96 + 64 + c4 * 4);
  }

  float a2[16];
  {
    const float4* ap = reinterpret_cast<const float4*>(A2 + (size_t)d * 16);
#pragma unroll
    for (int q = 0; q < 4; q++){
      const float4 v = ap[q];
      a2[q*4] = v.x; a2[q*4+1] = v.y; a2[q*4+2] = v.z; a2[q*4+3] = v.w;
    }
  }
  bool uni = true;
#pragma unroll
  for (int n = 1; n < 16; n++) uni = uni && (a2[n] == a2[0]);
  const float sgv = sg[d];
  const size_t xidx0 = (size_t)(b * 2048 + l0) * 1024 + d;
  const size_t base = ((size_t)((b * 64 + chunk) * 1024 + d)) * 16;

  __syncthreads();

  if (uni){
    const float a2u = a2[0];
    v2f h2[8];
#pragma unroll
    for (int q = 0; q < 8; q++) h2[q] = (v2f){0.f, 0.f};
    float sumd = 0.f;
    for (int ph = 0; ph < 2; ++ph){
      const size_t xidx = xidx0 + (size_t)ph * 16 * 1024;
      float dl[16], du[16];
#pragma unroll
      for (int li = 0; li < 16; ++li){
        dl[li] = del[xidx + (size_t)li * 1024];
        du[li] = dl[li] * x[xidx + (size_t)li * 1024] * sgv;
      }
#pragma unroll 4
      for (int li = 0; li < 16; ++li){
        sumd += dl[li];
        const float tt = fexp2(dl[li] * a2u);
        const v2f tt2 = {tt, tt}, du2 = {du[li], du[li]};
        const v2f* brow = reinterpret_cast<const v2f*>(&bsm[(ph * 16 + li) * 16]);
#pragma unroll
        for (int q = 0; q < 8; q++) h2[q] = h2[q] * tt2 + brow[q] * du2;
      }
    }
    const float4* hv = reinterpret_cast<const float4*>(h2);
#pragma unroll
    for (int q = 0; q < 4; q++)
      *reinterpret_cast<float4*>(&S[base + q * 4]) = hv[q];
    const float Ppu = fexp2(a2u * sumd);
    const float4 pv = {Ppu, Ppu, Ppu, Ppu};
#pragma unroll
    for (int q = 0; q < 4; q++)
      *reinterpret_cast<float4*>(&P[base + q * 4]) = pv;
  } else {
    float h[16], Pp[16];
#pragma unroll
    for (int n = 0; n < 16; n++){ h[n] = 0.f; Pp[n] = 1.f; }
    for (int li = 0; li < 32; ++li){
      const float dv = del[xidx0 + (size_t)li * 1024];
      const float duv = dv * x[xidx0 + (size_t)li * 1024] * sgv;
      const float* brow = &bsm[li * 16];
#pragma unroll
      for (int n = 0; n < 16; n++){
        const float tt = fexp2(dv * a2[n]);
        h[n] = fmaf(tt, h[n], duv * brow[n]);
        Pp[n] *= tt;
      }
    }
#pragma unroll
    for (int q = 0; q < 4; q++){
      float4 v; v.x = h[q*4]; v.y = h[q*4+1]; v.z = h[q*4+2]; v.w = h[q*4+3];
      *reinterpret_cast<float4*>(&S[base + q * 4]) = v;
      float4 u; u.x = Pp[q*4]; u.y = Pp[q*4+1]; u.z = Pp[q*4+2]; u.w = Pp[q*4+3];
      *reinterpret_cast<float4*>(&P[base + q * 4]) = u;
    }
  }
}

// ---------------- scan2: single-walk segmented combine, C=64. Grid 1024 x 256.
__global__ __launch_bounds__(256) void k_scan2(const float* __restrict__ S,
                                               const float* __restrict__ P,
                                               float* __restrict__ H){
  __shared__ float ls[256], lp[256];
  const int t = threadIdx.x;
  const int dn = t & 31, seg = t >> 5;
  const int n = dn & 15, dloc = dn >> 4;
  const int bid = blockIdx.x;
  const int b = bid >> 9, dpair = bid & 511;
  const int d = dpair * 2 + dloc;
  const size_t sbase = ((size_t)(b * 64) * 1024 + d) * 16 + n;  // + c*16384
  float Sv[8], Pv[8];
  float s = 0.f, p = 1.f;
#pragma unroll
  for (int i = 0; i < 8; i++){
    const size_t idx = sbase + (size_t)(seg * 8 + i) * 16384;
    Sv[i] = S[idx]; Pv[i] = P[idx];
    s = fmaf(Pv[i], s, Sv[i]);
    p *= Pv[i];
  }
  ls[t] = s; lp[t] = p;
  __syncthreads();
  float h = 0.f;
  for (int j = 0; j < seg; j++)
    h = fmaf(lp[j * 32 + dn], h, ls[j * 32 + dn]);
#pragma unroll
  for (int i = 0; i < 8; i++){
    const size_t idx = sbase + (size_t)(seg * 8 + i) * 16384;
    H[idx] = h;
    h = fmaf(Pv[i], h, Sv[i]);
  }
}

// ---------------- scan3: lean scan with true init + y, C=64, len=32.
// B+C rows staged in LDS (broadcast reads) instead of s_load chains.
__global__ __launch_bounds__(256) void k_scan3(const float* __restrict__ x,
                                               const float* __restrict__ del,
                                               const float* __restrict__ xz,
                                               const float* __restrict__ A2,
                                               const float* __restrict__ sg,
                                               const float* __restrict__ Dpar,
                                               const float* __restrict__ H,
                                               float* __restrict__ out){
  __shared__ float bcs[32 * 32];   // B,C rows [l][c] (B:0-15, C:16-31)  4 KB
  const int t = threadIdx.x;
  const int chunk = blockIdx.x, dgrp = blockIdx.y, b = blockIdx.z;
  const int d = dgrp * 256 + t;
  const int l0 = chunk * 32;
  const float* xzb = xz + (size_t)(b * 2048 + l0) * 96;

  // stage B+C slice: 32 rows x 8 float4 = 256 float4, one per thread
  {
    const int r = t >> 3, c4 = t & 7;
    *reinterpret_cast<float4*>(&bcs[r * 32 + c4 * 4]) =
      *reinterpret_cast<const float4*>(xzb + r * 96 + 64 + c4 * 4);
  }

  float a2[16];
  {
    const float4* ap = reinterpret_cast<const float4*>(A2 + (size_t)d * 16);
#pragma unroll
    for (int q = 0; q < 4; q++){
      const float4 v = ap[q];
      a2[q*4] = v.x; a2[q*4+1] = v.y; a2[q*4+2] = v.z; a2[q*4+3] = v.w;
    }
  }
  bool uni = true;
#pragma unroll
  for (int n = 1; n < 16; n++) uni = uni && (a2[n] == a2[0]);
  const float sgv = sg[d], Dv = Dpar[d];
  const size_t xidx0 = (size_t)(b * 2048 + l0) * 1024 + d;
  const size_t hbase = ((size_t)((b * 64 + chunk) * 1024 + d)) * 16;

  __syncthreads();

  if (uni){
    const float a2u = a2[0];
    v2f h2[8];
    {
      const float4* hp = reinterpret_cast<const float4*>(H + hbase);
      float4* hd = reinterpret_cast<float4*>(h2);
#pragma unroll
      for (int q = 0; q < 4; q++) hd[q] = hp[q];
    }
    for (int ph = 0; ph < 2; ++ph){
      const size_t xidx = xidx0 + (size_t)ph * 16 * 1024;
      float dl[16], xd[16];
#pragma unroll
      for (int li = 0; li < 16; ++li){
        dl[li] = del[xidx + (size_t)li * 1024];
        xd[li] = x[xidx + (size_t)li * 1024] * sgv;
      }
#pragma unroll 4
      for (int li = 0; li < 16; ++li){
        const float duv = dl[li] * xd[li];
        const float tt = fexp2(dl[li] * a2u);
        const v2f tt2 = {tt, tt}, du2 = {duv, duv};
        const v2f* brow = reinterpret_cast<const v2f*>(&bcs[(ph * 16 + li) * 32]);
        const v2f* crow = reinterpret_cast<const v2f*>(&bcs[(ph * 16 + li) * 32 + 16]);
        v2f yv = {0.f, 0.f};
#pragma unroll
        for (int q = 0; q < 8; q++){
          h2[q] = h2[q] * tt2 + brow[q] * du2;
          yv = yv + h2[q] * crow[q];
        }
        out[xidx + (size_t)li * 1024] = fmaf(xd[li], Dv, yv.x + yv.y);
      }
    }
  } else {
    float h[16];
    {
      const float4* hp = reinterpret_cast<const float4*>(H + hbase);
#pragma unroll
      for (int q = 0; q < 4; q++){
        const float4 v = hp[q];
        h[q*4] = v.x; h[q*4+1] = v.y; h[q*4+2] = v.z; h[q*4+3] = v.w;
      }
    }
    for (int li = 0; li < 32; ++li){
      const float dv = del[xidx0 + (size_t)li * 1024];
      const float xdv = x[xidx0 + (size_t)li * 1024] * sgv;
      const float duv = dv * xdv;
      const float* brow = &bcs[li * 32];
      float y = 0.f;
#pragma unroll
      for (int n = 0; n < 16; n++){
        const float tt = fexp2(dv * a2[n]);
        h[n] = fmaf(tt, h[n], duv * brow[n]);
        y = fmaf(h[n], brow[16 + n], y);
      }
      out[xidx0 + (size_t)li * 1024] = fmaf(xdv, Dv, y);
    }
  }
}

extern "C" void kernel_launch(void* const* d_in, const int* in_sizes, int n_in,
                              void* d_out, int out_size, void* d_ws, size_t ws_size,
                              hipStream_t stream){
  const float* x    = (const float*)d_in[0];
  const float* Alog = (const float*)d_in[1];
  const float* xpw  = (const float*)d_in[2];
  const float* dtw  = (const float*)d_in[3];
  const float* dtb  = (const float*)d_in[4];
  const float* Dpar = (const float*)d_in[5];
  const float* te   = (const float*)d_in[6];
  float* out = (float*)d_out;
  char* ws = (char*)d_ws;

  float* w2T  = (float*)(ws);             // 393216
  float* A2   = (float*)(ws + 393216);    // 65536
  float* sg   = (float*)(ws + 458752);    // 4096
  float* dtwT = (float*)(ws + 462848);    // 262144
  float* xz   = (float*)(ws + 724992);    // 1572864
  float* del  = (float*)(ws + 2297856);   // 16777216
  float* xzp  = (float*)(ws + 19075072);  // 12582912 (8 partials)
  float* S    = (float*)(ws + 31657984);  // 8388608 (B*64*D*N*4)
  float* P    = (float*)(ws + 40046592);  // 8388608
  float* Hst  = (float*)(ws + 48435200);  // 8388608 -> ends 56823808

  hipLaunchKernelGGL(k_prep,   dim3(177),        dim3(256), 0, stream, xpw, dtw, Alog, te, w2T, dtwT, A2, sg);
  hipLaunchKernelGGL(k_xz,     dim3(16, 3, 8),   dim3(256), 0, stream, x, w2T, xzp);
  hipLaunchKernelGGL(k_reduce, dim3(384),        dim3(256), 0, stream, (const float4*)xzp, (float4*)xz);
  hipLaunchKernelGGL(k_delta,  dim3(256, 4),     dim3(256), 0, stream, xz, dtwT, dtb, del);
  hipLaunchKernelGGL(k_scan1,  dim3(64, 4, 2),   dim3(256), 0, stream, x, del, xz, A2, sg, S, P);
  hipLaunchKernelGGL(k_scan2,  dim3(1024),       dim3(256), 0, stream, S, P, Hst);
  hipLaunchKernelGGL(k_scan3,  dim3(64, 4, 2),   dim3(256), 0, stream, x, del, xz, A2, sg, Dpar, Hst, out);
}